// Round 16
// baseline (815.532 us; speedup 1.0000x reference)
//
#include <hip/hip_runtime.h>
#include <hip/hip_bf16.h>

// BinaryLinear: C[M,N] = (x[M,K] @ sign(W)[N,K]^T) * scale + bias
// M=8192 K=4096 N=16384 fp32. Round 16: R13 pipeline + R11 loop cadence
// (BK=128 dbuf, full-iter vmcnt lead, 1 barrier/iter, verified staging),
// compute switched to mfma_i32_16x16x64_i8: 16-row frag span = R10's
// measured-ZERO-conflict read pattern (32x32's 32-row span measured a
// layout-invariant 4cyc/b128 penalty in R11/R12). Sum model predicts
// GEMM ~600 us (pipe +272, conflicts -768 cyc/tile).

typedef __attribute__((ext_vector_type(4))) float f32x4;
typedef __attribute__((ext_vector_type(4))) int i32x4;
typedef __attribute__((ext_vector_type(8))) short s16x8;
typedef __attribute__((ext_vector_type(4))) unsigned int u32x4;

#define AS1(p) ((const __attribute__((address_space(1))) void*)(p))
#define AS3(p) ((__attribute__((address_space(3))) void*)(p))

// ---------------- preprocessing (verified R13) ----------------

__global__ void __launch_bounds__(256) quant_rows(const float* __restrict__ x,
                                                  signed char* __restrict__ xq,
                                                  float* __restrict__ srow,
                                                  int M, int K) {
  const int lane = threadIdx.x & 63;
  const int wid = blockIdx.x * 4 + (threadIdx.x >> 6);
  const int nw = gridDim.x * 4;
  for (int r = wid; r < M; r += nw) {
    const float* row = x + (size_t)r * K;
    float m = 0.f;
    for (int k = lane * 8; k < K; k += 512) {
      const f32x4* p = (const f32x4*)(row + k);
      f32x4 v0 = p[0], v1 = p[1];
#pragma unroll
      for (int j = 0; j < 4; ++j) {
        m = fmaxf(m, fabsf(v0[j]));
        m = fmaxf(m, fabsf(v1[j]));
      }
    }
#pragma unroll
    for (int mask = 32; mask >= 1; mask >>= 1)
      m = fmaxf(m, __shfl_xor(m, mask, 64));
    const float si = (m > 0.f) ? (127.0f / m) : 0.f;
    if (lane == 0) srow[r] = m;
    signed char* qrow = xq + (size_t)r * K;
    for (int k = lane * 8; k < K; k += 512) {
      const f32x4* p = (const f32x4*)(row + k);
      f32x4 v0 = p[0], v1 = p[1];
      unsigned b[8];
#pragma unroll
      for (int j = 0; j < 4; ++j) {
        b[j] = (unsigned)((int)rintf(fminf(fmaxf(v0[j] * si, -127.f), 127.f))) & 255u;
        b[4 + j] = (unsigned)((int)rintf(fminf(fmaxf(v1[j] * si, -127.f), 127.f))) & 255u;
      }
      uint2 o;
      o.x = b[0] | (b[1] << 8) | (b[2] << 16) | (b[3] << 24);
      o.y = b[4] | (b[5] << 8) | (b[6] << 16) | (b[7] << 24);
      *(uint2*)(qrow + k) = o;
    }
  }
}

__global__ void __launch_bounds__(256) bin_w_i8(const unsigned* __restrict__ in,
                                                signed char* __restrict__ out,
                                                int n8) {
  int i = blockIdx.x * 256 + threadIdx.x;
  const int stride = gridDim.x * 256;
  for (; i < n8; i += stride) {
    const u32x4* p = (const u32x4*)in + (size_t)i * 2;
    u32x4 v0 = p[0], v1 = p[1];
    unsigned b[8];
#pragma unroll
    for (int j = 0; j < 4; ++j) {  // sign(0)=+1: byte = w<0 ? 0xFF : 0x01
      b[j] = 1u | ((unsigned)(((int)v0[j]) >> 31) & 0xFEu);
      b[4 + j] = 1u | ((unsigned)(((int)v1[j]) >> 31) & 0xFEu);
    }
    uint2 o;
    o.x = b[0] | (b[1] << 8) | (b[2] << 16) | (b[3] << 24);
    o.y = b[4] | (b[5] << 8) | (b[6] << 16) | (b[7] << 24);
    *(uint2*)(out + (size_t)i * 8) = o;
  }
}

// ---------------- i8 GEMM, BK=128, 16x16x64 frags ----------------
// LDS (128 KiB): buf{0,1} x {A 32 KB [256 rows x 128 B], B 32 KB} —
// STORE layout and staging identical to R11/R13 (verified):
//   row byte = row*128 + ((ch ^ (row&7))*16), ch = logical 16B chunk 0..7;
//   stage dest tid*16 linear, source logical ch kc2 = (tid&7)^((tid>>3)&7).
// READ (16x16x64, k-step s=0..1): lane -> row lr=lane&15 (16-row span),
//   logical ch = s*4 + lk (lk=lane>>4). Stored = (s<<2 ^ lk) ^ (lr&7)
//   -> per-lane base chb=(lk^(lr&7))*16, frag offset +idx*2048 (bit 11+,
//   no carry into XOR bits), addr ^= s<<6. Bank audit: per 16-lane
//   k-group stored chunks sweep all 8 groups twice -> 8 lanes/group,
//   8-cycle minimum (R10's 0-conflict pattern).
// Iter t: [stage t+1 (8 loads)] [2 k-steps x {12 ds_read_b128, 32 MFMA}]
//   [vmcnt(0): full-iteration-old loads] [BAR]. NT=32.

#define WAITV0() asm volatile("s_waitcnt vmcnt(0)" ::: "memory")
#define BAR()    __builtin_amdgcn_s_barrier()
#define LDSB ((const char*)lds)

#define STAGE_I8(bufo, koff)                                                   \
  do {                                                                         \
    _Pragma("unroll") for (int g = 0; g < 4; ++g)                              \
        __builtin_amdgcn_global_load_lds(                                      \
            AS1(sA + (long)g * 64 * Kb + (koff)),                              \
            AS3((char*)lds + (bufo) + g * 8192 + tid * 16), 16, 0, 0);         \
    _Pragma("unroll") for (int g = 0; g < 4; ++g)                              \
        __builtin_amdgcn_global_load_lds(                                      \
            AS1(sB + (long)g * 64 * Kb + (koff)),                              \
            AS3((char*)lds + (bufo) + 32768 + g * 8192 + tid * 16), 16, 0, 0); \
  } while (0)

__global__ void __launch_bounds__(512, 2)
gemm_i8(const signed char* __restrict__ A, const signed char* __restrict__ B,
        const float* __restrict__ scale, const float* __restrict__ bias,
        const float* __restrict__ srow, float* __restrict__ C,
        const int M, const int N, const int K) {
  __shared__ signed char lds[131072];  // 128 KiB
  const int tid = threadIdx.x;
  const int lane = tid & 63;
  const int wv = tid >> 6;   // 0..7
  const int wm = wv >> 2;    // 0..1
  const int wn = wv & 3;     // 0..3
  const int lr = lane & 15, lk = lane >> 4;

  // XCD-aware swizzle (bijective: nwg % 8 == 0)
  const int mt = M >> 8, nt = N >> 8;
  const int nwg = mt * nt;
  const int orig = blockIdx.x;
  const int wg = (nwg & 7) ? orig : ((orig & 7) * (nwg >> 3) + (orig >> 3));
  const int bm = wg % mt;
  const int bn = wg / mt;
  const int rA0 = bm * 256, rB0 = bn * 256;

  // ds_read bases (16x16 pattern): row*128 + ((lk ^ (lr&7))*16)
  const int chb = (lk ^ (lr & 7)) * 16;
  const int rdA = (wm * 128 + lr) * 128 + chb;
  const int rdB = 32768 + (wn * 64 + lr) * 128 + chb;

  // stage source base (inverse-swizzled, R11-verified)
  const int kc2 = (tid & 7) ^ ((tid >> 3) & 7);
  const long Kb = (long)K;  // bytes per row (i8)
  const signed char* sA = A + (long)(rA0 + (tid >> 3)) * Kb + kc2 * 16;
  const signed char* sB = B + (long)(rB0 + (tid >> 3)) * Kb + kc2 * 16;

  i32x4 acc[8][4] = {};
  const int NT = K >> 7;  // 32

  // prologue: tile 0 -> buf0
  STAGE_I8(0, 0);
  WAITV0();
  BAR();

  for (int t = 0; t < NT; ++t) {
    const int bufR = (t & 1) << 16;
    const int bufW = bufR ^ 65536;
    int tt = t + 1; if (tt == NT) tt = 0;  // wrapped final stage (harmless)
    STAGE_I8(bufW, (long)tt * 128);

#pragma unroll
    for (int s = 0; s < 2; ++s) {
      const int sx = s << 6;
      i32x4 a[8], b[4];
#pragma unroll
      for (int nj = 0; nj < 4; ++nj)
        b[nj] = *(const i32x4*)(LDSB + bufR + ((rdB + nj * 2048) ^ sx));
#pragma unroll
      for (int mi = 0; mi < 8; ++mi)
        a[mi] = *(const i32x4*)(LDSB + bufR + ((rdA + mi * 2048) ^ sx));
#pragma unroll
      for (int mi = 0; mi < 8; ++mi)
#pragma unroll
        for (int nj = 0; nj < 4; ++nj)
          acc[mi][nj] = __builtin_amdgcn_mfma_i32_16x16x64_i8(
              a[mi], b[nj], acc[mi][nj], 0, 0, 0);
    }

    WAITV0();  // retires tile t+1's 8 loads (issued a full iteration ago)
    BAR();     // publish buf[t+1]
  }

  // epilogue: C[m][n] = acc * (srow[m]/127 * scale) + bias[n]
  // 16x16 C/D (verified): col = lane&15, row = (lane>>4)*4 + reg
  const float s127 = scale[0] * (1.0f / 127.0f);
  const int n0 = rB0 + wn * 64 + lr;
  float bb[4];
#pragma unroll
  for (int nj = 0; nj < 4; ++nj) bb[nj] = bias[n0 + nj * 16];
#pragma unroll
  for (int mi = 0; mi < 8; ++mi) {
#pragma unroll
    for (int rg = 0; rg < 4; ++rg) {
      const int row = rA0 + wm * 128 + mi * 16 + lk * 4 + rg;
      const float sv = srow[row] * s127;
      float* crow = C + (size_t)row * N + n0;
#pragma unroll
      for (int nj = 0; nj < 4; ++nj)
        crow[nj * 16] = (float)acc[mi][nj][rg] * sv + bb[nj];
    }
  }
}

// ---------------- no-workspace fallback (bf16 MFMA, in-kernel convert) ----
__device__ __forceinline__ unsigned short f2bf(float f) {
  unsigned u = __float_as_uint(f);
  u += 0x7FFFu + ((u >> 16) & 1u);
  return (unsigned short)(u >> 16);
}

__global__ void __launch_bounds__(256, 2)
gemm_fallback(const float* __restrict__ Ap, const float* __restrict__ Bp,
              const float* __restrict__ scale, const float* __restrict__ bias,
              float* __restrict__ C, const int M, const int N, const int K) {
  __shared__ unsigned short As[128 * 64];
  __shared__ unsigned short Bs[128 * 64];
  const int tid = threadIdx.x;
  const int lane = tid & 63;
  const int wv = tid >> 6;
  const int wm = wv >> 1, wn = wv & 1;
  const int bn = blockIdx.x, bm = blockIdx.y;
  const int lr = lane & 15, lk = lane >> 4;
  f32x4 acc[4][4] = {};
  const int rA0 = bm * 128, rB0 = bn * 128;

  for (int k0 = 0; k0 < K; k0 += 64) {
#pragma unroll
    for (int i = 0; i < 4; ++i) {
      const int c = i * 256 + tid;
      const int row = c >> 3, kc = c & 7;
      const f32x4* srcA = (const f32x4*)(Ap + (size_t)(rA0 + row) * K + (k0 + kc * 8));
      f32x4 v0 = srcA[0], v1 = srcA[1];
      s16x8 o;
      o[0] = (short)f2bf(v0[0]); o[1] = (short)f2bf(v0[1]);
      o[2] = (short)f2bf(v0[2]); o[3] = (short)f2bf(v0[3]);
      o[4] = (short)f2bf(v1[0]); o[5] = (short)f2bf(v1[1]);
      o[6] = (short)f2bf(v1[2]); o[7] = (short)f2bf(v1[3]);
      *(s16x8*)&As[(row * 8 + (kc ^ (row & 7))) * 8] = o;
      const u32x4* srcB =
          (const u32x4*)(Bp + (size_t)(rB0 + row) * K + (k0 + kc * 8));
      u32x4 w0 = srcB[0], w1 = srcB[1];
      s16x8 ob;
      ob[0] = (short)(0x3F80u | ((w0[0] >> 16) & 0x8000u));
      ob[1] = (short)(0x3F80u | ((w0[1] >> 16) & 0x8000u));
      ob[2] = (short)(0x3F80u | ((w0[2] >> 16) & 0x8000u));
      ob[3] = (short)(0x3F80u | ((w0[3] >> 16) & 0x8000u));
      ob[4] = (short)(0x3F80u | ((w1[0] >> 16) & 0x8000u));
      ob[5] = (short)(0x3F80u | ((w1[1] >> 16) & 0x8000u));
      ob[6] = (short)(0x3F80u | ((w1[2] >> 16) & 0x8000u));
      ob[7] = (short)(0x3F80u | ((w1[3] >> 16) & 0x8000u));
      *(s16x8*)&Bs[(row * 8 + (kc ^ (row & 7))) * 8] = ob;
    }
    __syncthreads();
#pragma unroll
    for (int ks = 0; ks < 2; ++ks) {
      s16x8 a[4], b[4];
#pragma unroll
      for (int mi = 0; mi < 4; ++mi) {
        const int row = wm * 64 + mi * 16 + lr;
        const int kc = ks * 4 + lk;
        a[mi] = *(const s16x8*)&As[(row * 8 + (kc ^ (row & 7))) * 8];
      }
#pragma unroll
      for (int ni = 0; ni < 4; ++ni) {
        const int row = wn * 64 + ni * 16 + lr;
        const int kc = ks * 4 + lk;
        b[ni] = *(const s16x8*)&Bs[(row * 8 + (kc ^ (row & 7))) * 8];
      }
#pragma unroll
      for (int mi = 0; mi < 4; ++mi)
#pragma unroll
        for (int ni = 0; ni < 4; ++ni)
          acc[mi][ni] = __builtin_amdgcn_mfma_f32_16x16x32_bf16(a[mi], b[ni],
                                                               acc[mi][ni], 0, 0, 0);
    }
    __syncthreads();
  }

  const float s = scale[0];
  const int n0 = rB0 + wn * 64 + lr;
  const int m0 = rA0 + wm * 64 + lk * 4;
  float bb[4];
#pragma unroll
  for (int ni = 0; ni < 4; ++ni) bb[ni] = bias[n0 + ni * 16];
#pragma unroll
  for (int mi = 0; mi < 4; ++mi) {
#pragma unroll
    for (int r = 0; r < 4; ++r) {
      float* crow = C + (size_t)(m0 + mi * 16 + r) * N + n0;
#pragma unroll
      for (int ni = 0; ni < 4; ++ni)
        crow[ni * 16] = acc[mi][ni][r] * s + bb[ni];
    }
  }
}

extern "C" void kernel_launch(void* const* d_in, const int* in_sizes, int n_in,
                              void* d_out, int out_size, void* d_ws, size_t ws_size,
                              hipStream_t stream) {
  const float* x = (const float*)d_in[0];
  const float* w = (const float*)d_in[1];
  const float* scale = (const float*)d_in[2];
  const float* bias = (const float*)d_in[3];
  float* out = (float*)d_out;

  const int K = 4096;
  const int M = in_sizes[0] / K;  // 8192
  const int N = in_sizes[3];      // 16384

  const size_t MK = (size_t)M * K, NK = (size_t)N * K;
  const size_t srowB = (((size_t)M * 4 + 255) / 256) * 256;  // aligned
  const size_t need = srowB + MK + NK;  // srow + x_i8 + w_i8 (~96 MB)

  if (ws_size >= need && (M % 256) == 0 && (N % 256) == 0 && (K % 128) == 0 &&
      (K % 8) == 0 && (K / 128) >= 2) {
    float* srow = (float*)d_ws;
    signed char* xq = (signed char*)d_ws + srowB;
    signed char* wq = (signed char*)d_ws + srowB + MK;
    quant_rows<<<2048, 256, 0, stream>>>(x, xq, srow, M, K);
    bin_w_i8<<<2048, 256, 0, stream>>>((const unsigned*)w, wq, (int)(NK / 8));
    gemm_i8<<<dim3((M / 256) * (N / 256)), 512, 0, stream>>>(
        xq, wq, scale, bias, srow, out, M, N, K);
  } else {
    gemm_fallback<<<dim3(N / 128, M / 128), 256, 0, stream>>>(
        x, w, scale, bias, out, M, N, K);
  }
}

// Round 17
// 755.311 us; speedup vs baseline: 1.0797x; 1.0797x over previous
//
#include <hip/hip_runtime.h>
#include <hip/hip_bf16.h>

// BinaryLinear: C[M,N] = (x[M,K] @ sign(W)[N,K]^T) * scale + bias
// M=8192 K=4096 N=16384 fp32. Round 17 (final config): best-measured GEMM
// (R11/R13/R15: i8, 256x256, 8 waves, mfma_i32_32x32x32_i8, BK=128 dbuf,
// 128-B-row LDS ch^=row&7 swizzle, full-iter vmcnt lead — 640-655 us;
// R16 proved the 5.03e7 conflict cycles are HIDDEN: removing them via
// 16x16 frags gained 0 and cost +270cyc/tile pipe). Preprocessing merged
// into ONE kernel (disjoint block ranges run the verified quant-rows and
// binarize-W bodies) to drop a launch boundary. absmax 3.75 (thr 7.16).

typedef __attribute__((ext_vector_type(4))) float f32x4;
typedef __attribute__((ext_vector_type(4))) int i32x4;
typedef __attribute__((ext_vector_type(16))) int i32x16;
typedef __attribute__((ext_vector_type(8))) short s16x8;
typedef __attribute__((ext_vector_type(4))) unsigned int u32x4;

#define AS1(p) ((const __attribute__((address_space(1))) void*)(p))
#define AS3(p) ((__attribute__((address_space(3))) void*)(p))

// ---------------- merged preprocessing ----------------
// Blocks [0, QB): per-row x quantization (one wave per row, shfl absmax,
// quantize; row 16 KB -> 2nd read L1/L2-hot). Blocks [QB, QB+WB): W
// binarize to +-1 i8. Both bodies verbatim from R13 (verified).

__global__ void __launch_bounds__(256)
prep_all(const float* __restrict__ x, signed char* __restrict__ xq,
         float* __restrict__ srow, const unsigned* __restrict__ w,
         signed char* __restrict__ wq, int M, int K, int nw8, int QB) {
  if ((int)blockIdx.x < QB) {
    const int lane = threadIdx.x & 63;
    const int wid = blockIdx.x * 4 + (threadIdx.x >> 6);
    const int nw = QB * 4;
    for (int r = wid; r < M; r += nw) {
      const float* row = x + (size_t)r * K;
      float m = 0.f;
      for (int k = lane * 8; k < K; k += 512) {
        const f32x4* p = (const f32x4*)(row + k);
        f32x4 v0 = p[0], v1 = p[1];
#pragma unroll
        for (int j = 0; j < 4; ++j) {
          m = fmaxf(m, fabsf(v0[j]));
          m = fmaxf(m, fabsf(v1[j]));
        }
      }
#pragma unroll
      for (int mask = 32; mask >= 1; mask >>= 1)
        m = fmaxf(m, __shfl_xor(m, mask, 64));
      const float si = (m > 0.f) ? (127.0f / m) : 0.f;
      if (lane == 0) srow[r] = m;
      signed char* qrow = xq + (size_t)r * K;
      for (int k = lane * 8; k < K; k += 512) {
        const f32x4* p = (const f32x4*)(row + k);
        f32x4 v0 = p[0], v1 = p[1];
        unsigned b[8];
#pragma unroll
        for (int j = 0; j < 4; ++j) {
          b[j] = (unsigned)((int)rintf(fminf(fmaxf(v0[j] * si, -127.f), 127.f))) & 255u;
          b[4 + j] = (unsigned)((int)rintf(fminf(fmaxf(v1[j] * si, -127.f), 127.f))) & 255u;
        }
        uint2 o;
        o.x = b[0] | (b[1] << 8) | (b[2] << 16) | (b[3] << 24);
        o.y = b[4] | (b[5] << 8) | (b[6] << 16) | (b[7] << 24);
        *(uint2*)(qrow + k) = o;
      }
    }
  } else {
    const int bid = (int)blockIdx.x - QB;
    const int WB = (int)gridDim.x - QB;
    int i = bid * 256 + threadIdx.x;
    const int stride = WB * 256;
    for (; i < nw8; i += stride) {
      const u32x4* p = (const u32x4*)w + (size_t)i * 2;
      u32x4 v0 = p[0], v1 = p[1];
      unsigned b[8];
#pragma unroll
      for (int j = 0; j < 4; ++j) {  // sign(0)=+1: byte = w<0 ? 0xFF : 0x01
        b[j] = 1u | ((unsigned)(((int)v0[j]) >> 31) & 0xFEu);
        b[4 + j] = 1u | ((unsigned)(((int)v1[j]) >> 31) & 0xFEu);
      }
      uint2 o;
      o.x = b[0] | (b[1] << 8) | (b[2] << 16) | (b[3] << 24);
      o.y = b[4] | (b[5] << 8) | (b[6] << 16) | (b[7] << 24);
      *(uint2*)(wq + (size_t)i * 8) = o;
    }
  }
}

// ---------------- i8 GEMM: R11/R13/R15 verbatim (640-655 us) ---------------
// LDS (128 KiB): buf{0,1} x {A 32 KB [256 rows x 128 B], B 32 KB}.
//   row byte = row*128 + ((ch ^ (row&7))*16), ch = logical 16B chunk 0..7.
// Frag (32x32x32): lane -> row l31, 16B chunk (s<<1)|(lane>>5);
//   addr(s) = rd ^ (s<<5). Stage: dest tid*16 linear; source logical ch
//   kc2 = (tid&7)^((tid>>3)&7). Iter: [stage t+1 (8 loads)] [4 k-steps x
//   {6 ds_read_b128, 8 MFMA}] [vmcnt(0): full-iteration-old loads] [BAR].

#define WAITV0() asm volatile("s_waitcnt vmcnt(0)" ::: "memory")
#define BAR()    __builtin_amdgcn_s_barrier()
#define LDSB ((const char*)lds)

#define STAGE_I8(bufo, koff)                                                   \
  do {                                                                         \
    _Pragma("unroll") for (int g = 0; g < 4; ++g)                              \
        __builtin_amdgcn_global_load_lds(                                      \
            AS1(sA + (long)g * 64 * Kb + (koff)),                              \
            AS3((char*)lds + (bufo) + g * 8192 + tid * 16), 16, 0, 0);         \
    _Pragma("unroll") for (int g = 0; g < 4; ++g)                              \
        __builtin_amdgcn_global_load_lds(                                      \
            AS1(sB + (long)g * 64 * Kb + (koff)),                              \
            AS3((char*)lds + (bufo) + 32768 + g * 8192 + tid * 16), 16, 0, 0); \
  } while (0)

__global__ void __launch_bounds__(512, 2)
gemm_i8(const signed char* __restrict__ A, const signed char* __restrict__ B,
        const float* __restrict__ scale, const float* __restrict__ bias,
        const float* __restrict__ srow, float* __restrict__ C,
        const int M, const int N, const int K) {
  __shared__ signed char lds[131072];  // 128 KiB
  const int tid = threadIdx.x;
  const int lane = tid & 63;
  const int wv = tid >> 6;   // 0..7
  const int wm = wv >> 2;    // 0..1
  const int wn = wv & 3;     // 0..3
  const int l31 = lane & 31, l5 = lane >> 5;

  // XCD-aware swizzle (bijective: nwg % 8 == 0)
  const int mt = M >> 8, nt = N >> 8;
  const int nwg = mt * nt;
  const int orig = blockIdx.x;
  const int wg = (nwg & 7) ? orig : ((orig & 7) * (nwg >> 3) + (orig >> 3));
  const int bm = wg % mt;
  const int bn = wg / mt;
  const int rA0 = bm * 256, rB0 = bn * 256;

  // ds_read bases: row*128 + ((l5 ^ (row&7))*16); row&7 == l31&7
  const int chb = (l5 ^ (l31 & 7)) * 16;
  const int rdA = (wm * 128 + l31) * 128 + chb;
  const int rdB = 32768 + (wn * 64 + l31) * 128 + chb;

  // stage source base (inverse-swizzled)
  const int kc2 = (tid & 7) ^ ((tid >> 3) & 7);
  const long Kb = (long)K;  // bytes per row (i8)
  const signed char* sA = A + (long)(rA0 + (tid >> 3)) * Kb + kc2 * 16;
  const signed char* sB = B + (long)(rB0 + (tid >> 3)) * Kb + kc2 * 16;

  i32x16 acc[4][2] = {};
  const int NT = K >> 7;  // 32

  // prologue: tile 0 -> buf0
  STAGE_I8(0, 0);
  WAITV0();
  BAR();

  for (int t = 0; t < NT; ++t) {
    const int bufR = (t & 1) << 16;
    const int bufW = bufR ^ 65536;
    int tt = t + 1; if (tt == NT) tt = 0;  // wrapped final stage (harmless)
    STAGE_I8(bufW, (long)tt * 128);

#pragma unroll
    for (int s = 0; s < 4; ++s) {
      const int sx = s << 5;
      i32x4 a[4], b[2];
#pragma unroll
      for (int nj = 0; nj < 2; ++nj)
        b[nj] = *(const i32x4*)(LDSB + bufR + ((rdB + nj * 4096) ^ sx));
#pragma unroll
      for (int mi = 0; mi < 4; ++mi)
        a[mi] = *(const i32x4*)(LDSB + bufR + ((rdA + mi * 4096) ^ sx));
#pragma unroll
      for (int mi = 0; mi < 4; ++mi)
#pragma unroll
        for (int nj = 0; nj < 2; ++nj)
          acc[mi][nj] = __builtin_amdgcn_mfma_i32_32x32x32_i8(
              a[mi], b[nj], acc[mi][nj], 0, 0, 0);
    }

    WAITV0();  // retires tile t+1's 8 loads (issued a full iteration ago)
    BAR();     // publish buf[t+1]
  }

  // epilogue: C[m][n] = acc * (srow[m]/127 * scale) + bias[n]
  // 32x32 C/D (verified): col = lane&31, row = (r&3)+8*(r>>2)+4*(lane>>5)
  const float s127 = scale[0] * (1.0f / 127.0f);
  const int n0 = rB0 + wn * 64 + l31;
  float bb[2];
  bb[0] = bias[n0];
  bb[1] = bias[n0 + 32];
  const int m0 = rA0 + wm * 128 + 4 * l5;
#pragma unroll
  for (int mi = 0; mi < 4; ++mi) {
#pragma unroll
    for (int r = 0; r < 16; ++r) {
      const int row = m0 + mi * 32 + (r & 3) + 8 * (r >> 2);
      const float sv = srow[row] * s127;
#pragma unroll
      for (int nj = 0; nj < 2; ++nj)
        C[(size_t)row * N + n0 + nj * 32] = (float)acc[mi][nj][r] * sv + bb[nj];
    }
  }
}

// ---------------- no-workspace fallback (bf16 MFMA, in-kernel convert) ----
__device__ __forceinline__ unsigned short f2bf(float f) {
  unsigned u = __float_as_uint(f);
  u += 0x7FFFu + ((u >> 16) & 1u);
  return (unsigned short)(u >> 16);
}

__global__ void __launch_bounds__(256, 2)
gemm_fallback(const float* __restrict__ Ap, const float* __restrict__ Bp,
              const float* __restrict__ scale, const float* __restrict__ bias,
              float* __restrict__ C, const int M, const int N, const int K) {
  __shared__ unsigned short As[128 * 64];
  __shared__ unsigned short Bs[128 * 64];
  const int tid = threadIdx.x;
  const int lane = tid & 63;
  const int wv = tid >> 6;
  const int wm = wv >> 1, wn = wv & 1;
  const int bn = blockIdx.x, bm = blockIdx.y;
  const int lr = lane & 15, lk = lane >> 4;
  f32x4 acc[4][4] = {};
  const int rA0 = bm * 128, rB0 = bn * 128;

  for (int k0 = 0; k0 < K; k0 += 64) {
#pragma unroll
    for (int i = 0; i < 4; ++i) {
      const int c = i * 256 + tid;
      const int row = c >> 3, kc = c & 7;
      const f32x4* srcA = (const f32x4*)(Ap + (size_t)(rA0 + row) * K + (k0 + kc * 8));
      f32x4 v0 = srcA[0], v1 = srcA[1];
      s16x8 o;
      o[0] = (short)f2bf(v0[0]); o[1] = (short)f2bf(v0[1]);
      o[2] = (short)f2bf(v0[2]); o[3] = (short)f2bf(v0[3]);
      o[4] = (short)f2bf(v1[0]); o[5] = (short)f2bf(v1[1]);
      o[6] = (short)f2bf(v1[2]); o[7] = (short)f2bf(v1[3]);
      *(s16x8*)&As[(row * 8 + (kc ^ (row & 7))) * 8] = o;
      const u32x4* srcB =
          (const u32x4*)(Bp + (size_t)(rB0 + row) * K + (k0 + kc * 8));
      u32x4 w0 = srcB[0], w1 = srcB[1];
      s16x8 ob;
      ob[0] = (short)(0x3F80u | ((w0[0] >> 16) & 0x8000u));
      ob[1] = (short)(0x3F80u | ((w0[1] >> 16) & 0x8000u));
      ob[2] = (short)(0x3F80u | ((w0[2] >> 16) & 0x8000u));
      ob[3] = (short)(0x3F80u | ((w0[3] >> 16) & 0x8000u));
      ob[4] = (short)(0x3F80u | ((w1[0] >> 16) & 0x8000u));
      ob[5] = (short)(0x3F80u | ((w1[1] >> 16) & 0x8000u));
      ob[6] = (short)(0x3F80u | ((w1[2] >> 16) & 0x8000u));
      ob[7] = (short)(0x3F80u | ((w1[3] >> 16) & 0x8000u));
      *(s16x8*)&Bs[(row * 8 + (kc ^ (row & 7))) * 8] = ob;
    }
    __syncthreads();
#pragma unroll
    for (int ks = 0; ks < 2; ++ks) {
      s16x8 a[4], b[4];
#pragma unroll
      for (int mi = 0; mi < 4; ++mi) {
        const int row = wm * 64 + mi * 16 + lr;
        const int kc = ks * 4 + lk;
        a[mi] = *(const s16x8*)&As[(row * 8 + (kc ^ (row & 7))) * 8];
      }
#pragma unroll
      for (int ni = 0; ni < 4; ++ni) {
        const int row = wn * 64 + ni * 16 + lr;
        const int kc = ks * 4 + lk;
        b[ni] = *(const s16x8*)&Bs[(row * 8 + (kc ^ (row & 7))) * 8];
      }
#pragma unroll
      for (int mi = 0; mi < 4; ++mi)
#pragma unroll
        for (int ni = 0; ni < 4; ++ni)
          acc[mi][ni] = __builtin_amdgcn_mfma_f32_16x16x32_bf16(a[mi], b[ni],
                                                               acc[mi][ni], 0, 0, 0);
    }
    __syncthreads();
  }

  const float s = scale[0];
  const int n0 = rB0 + wn * 64 + lr;
  const int m0 = rA0 + wm * 64 + lk * 4;
  float bb[4];
#pragma unroll
  for (int ni = 0; ni < 4; ++ni) bb[ni] = bias[n0 + ni * 16];
#pragma unroll
  for (int mi = 0; mi < 4; ++mi) {
#pragma unroll
    for (int r = 0; r < 4; ++r) {
      float* crow = C + (size_t)(m0 + mi * 16 + r) * N + n0;
#pragma unroll
      for (int ni = 0; ni < 4; ++ni)
        crow[ni * 16] = acc[mi][ni][r] * s + bb[ni];
    }
  }
}

extern "C" void kernel_launch(void* const* d_in, const int* in_sizes, int n_in,
                              void* d_out, int out_size, void* d_ws, size_t ws_size,
                              hipStream_t stream) {
  const float* x = (const float*)d_in[0];
  const float* w = (const float*)d_in[1];
  const float* scale = (const float*)d_in[2];
  const float* bias = (const float*)d_in[3];
  float* out = (float*)d_out;

  const int K = 4096;
  const int M = in_sizes[0] / K;  // 8192
  const int N = in_sizes[3];      // 16384

  const size_t MK = (size_t)M * K, NK = (size_t)N * K;
  const size_t srowB = (((size_t)M * 4 + 255) / 256) * 256;  // aligned
  const size_t need = srowB + MK + NK;  // srow + x_i8 + w_i8 (~96 MB)

  if (ws_size >= need && (M % 256) == 0 && (N % 256) == 0 && (K % 128) == 0 &&
      (K % 8) == 0 && (M % 4) == 0 && (K / 128) >= 2) {
    float* srow = (float*)d_ws;
    signed char* xq = (signed char*)d_ws + srowB;
    signed char* wq = (signed char*)d_ws + srowB + MK;
    const int QB = (M + 3) / 4;          // one wave per row, 4 waves/block
    const int WB = 2048;                 // grid-stride W binarize
    prep_all<<<QB + WB, 256, 0, stream>>>(x, xq, srow, (const unsigned*)w, wq,
                                          M, K, (int)(NK / 8), QB);
    gemm_i8<<<dim3((M / 256) * (N / 256)), 512, 0, stream>>>(
        xq, wq, scale, bias, srow, out, M, N, K);
  } else {
    gemm_fallback<<<dim3(N / 128, M / 128), 256, 0, stream>>>(
        x, w, scale, bias, out, M, N, K);
  }
}